// Round 8
// baseline (376.162 us; speedup 1.0000x reference)
//
#include <hip/hip_runtime.h>

// GAT forward, CSR-by-dst via XCD-local binned counting sort:
//   h = x@W1; a[n]=h[n]·Wp[:64]; b[n]=h[n]·Wp[64:]
//   num_e = exp(leakyrelu(a[dst]+b[src]+bp))
//   denom[n] = sum_{e:dst=n} num_e
//   hh[n]   = h[n] / (denom[n]+1e-16)       (bf16, in-place over h rows)
//   out[n]  = sum_{e:dst=n} num_e * hh[src_e] + bias  (denom at SRC = ref quirk)
// Sort: edges -> (256-node dst-bin x 8 xcd-label) staging regions (sequential
// fill => single-L2 line merging), then per-bin LDS counting sort writes exact
// dst order in place and emits global CSR offsets. No random global scatter.

static __device__ __forceinline__ float bf2f(unsigned short u) {
    unsigned v = (unsigned)u << 16;
    return __builtin_bit_cast(float, v);
}
static __device__ __forceinline__ unsigned short f2bf(float f) {
    unsigned u = __builtin_bit_cast(unsigned, f);
    u = (u + 0x7FFFu + ((u >> 16) & 1u)) >> 16;   // round-to-nearest-even
    return (unsigned short)u;
}

// ---------------- node transform: h = x@W1, a,b projections ----------------
__global__ __launch_bounds__(256) void node_transform_kernel(
    const float* __restrict__ x, const float* __restrict__ W1,
    const float* __restrict__ Wp,
    float* __restrict__ h, float* __restrict__ aArr, float* __restrict__ bArr,
    int N)
{
    __shared__ float sW1t[64 * 132];   // [o][k], 33 KB
    const int tid = threadIdx.x;
    const int w = tid >> 6, lane = tid & 63;

    for (int i = tid; i < 128 * 64; i += 256)
        sW1t[(i & 63) * 132 + (i >> 6)] = W1[i];

    const float wpa = Wp[lane];
    const float wpb = Wp[64 + lane];
    __syncthreads();

    const int n0 = __builtin_amdgcn_readfirstlane(blockIdx.x * 16 + w * 4);
    const float* xp0 = x + (size_t)n0 * 128;

    float acc[4] = {0.f, 0.f, 0.f, 0.f};
    #pragma unroll 4
    for (int k4 = 0; k4 < 32; ++k4) {
        float4 wv = *reinterpret_cast<const float4*>(&sW1t[lane * 132 + k4 * 4]);
        #pragma unroll
        for (int m = 0; m < 4; ++m) {
            float4 xv = *reinterpret_cast<const float4*>(xp0 + m * 128 + k4 * 4);
            acc[m] = fmaf(xv.x, wv.x, acc[m]);
            acc[m] = fmaf(xv.y, wv.y, acc[m]);
            acc[m] = fmaf(xv.z, wv.z, acc[m]);
            acc[m] = fmaf(xv.w, wv.w, acc[m]);
        }
    }

    #pragma unroll
    for (int m = 0; m < 4; ++m) {
        const int n = n0 + m;
        h[(size_t)n * 64 + lane] = acc[m];
        float a = acc[m] * wpa, b = acc[m] * wpb;
        #pragma unroll
        for (int off = 32; off; off >>= 1) {
            a += __shfl_down(a, off);
            b += __shfl_down(b, off);
        }
        if (lane == 0) { aArr[n] = a; bArr[n] = b; }
    }
}

// ---------------- sub-bin histogram: (dst>>8) x (blockIdx&7) ----------------
__global__ __launch_bounds__(256) void subhist_kernel(
    const int* __restrict__ ei, int* __restrict__ cnt2, int E)
{
    int e = blockIdx.x * blockDim.x + threadIdx.x;
    if (e >= E) return;
    int dst = ei[E + e];
    atomicAdd(&cnt2[(dst >> 8) * 8 + (blockIdx.x & 7)], 1);
}

// -------- scan over M=K*8 sub-bins (1 block); also sentinels --------
__global__ __launch_bounds__(256) void subscan_kernel(
    const int* __restrict__ cnt2, int* __restrict__ subOffsets,
    int* __restrict__ subCursor, int* __restrict__ offsets,
    int M, int N, int E)
{
    __shared__ int ts[256];
    const int t = threadIdx.x;
    const int chunk = (M + 255) >> 8;
    const int base = t * chunk, lim = min(M, base + chunk);
    int s = 0;
    for (int i = base; i < lim; ++i) s += cnt2[i];
    ts[t] = s;
    __syncthreads();
    for (int off = 1; off < 256; off <<= 1) {
        int u = (t >= off) ? ts[t - off] : 0;
        __syncthreads();
        ts[t] += u;
        __syncthreads();
    }
    int run = ts[t] - s;   // exclusive
    for (int i = base; i < lim; ++i) {
        subOffsets[i] = run; subCursor[i] = run;
        run += cnt2[i];
    }
    if (t == 0) { subOffsets[M] = E; offsets[N] = E; }
}

// ---------------- binscatter: edges -> sub-bin staging (sequential fill) ----
__global__ __launch_bounds__(256) void binscatter_kernel(
    const int* __restrict__ ei, const float* __restrict__ aArr,
    const float* __restrict__ bArr, const float* __restrict__ bp,
    int* __restrict__ subCursor, int2* __restrict__ staging, int E)
{
    int e = blockIdx.x * blockDim.x + threadIdx.x;
    if (e >= E) return;
    int src = ei[e];
    int dst = ei[E + e];
    float s = aArr[dst] + bArr[src] + bp[0];
    s = (s >= 0.f) ? s : 0.2f * s;
    float num = __expf(s);
    int sb = (dst >> 8) * 8 + (blockIdx.x & 7);
    int pos = atomicAdd(&subCursor[sb], 1);
    staging[pos] = make_int2(((dst & 255) << 17) | src, __float_as_int(num));
}

// -------- localsort: one block per bin; exact dst order + CSR offsets -------
#define BIN_CAP 4096
__global__ __launch_bounds__(256) void localsort_kernel(
    const int* __restrict__ subOffsets, int2* __restrict__ staging,
    int* __restrict__ offsets, int N)
{
    __shared__ int2 sEnt[BIN_CAP];       // 32 KB
    __shared__ int sCnt[256], sScan[256], sCur[256];
    const int bin = blockIdx.x, t = threadIdx.x;
    const int binStart = bin << 8;
    const int Cl = min(256, N - binStart);
    const int sBeg = subOffsets[bin * 8];
    const int count = min(subOffsets[(bin + 1) * 8] - sBeg, BIN_CAP);

    sCnt[t] = 0; sCur[t] = 0;
    __syncthreads();
    for (int i = t; i < count; i += 256) {
        int2 e = staging[sBeg + i];
        sEnt[i] = e;
        atomicAdd(&sCnt[e.x >> 17], 1);
    }
    __syncthreads();
    int v = sCnt[t];
    sScan[t] = v;
    __syncthreads();
    for (int off = 1; off < 256; off <<= 1) {
        int u = (t >= off) ? sScan[t - off] : 0;
        __syncthreads();
        sScan[t] += u;
        __syncthreads();
    }
    int ex = sScan[t] - v;
    __syncthreads();
    sScan[t] = ex;                       // exclusive scan in place
    if (t < Cl) offsets[binStart + t] = sBeg + ex;
    __syncthreads();
    for (int i = t; i < count; i += 256) {
        int2 e = sEnt[i];
        int dl = e.x >> 17;
        int pos = sBeg + sScan[dl] + atomicAdd(&sCur[dl], 1);
        staging[pos] = make_int2(e.x & 0x1FFFF, e.y);   // {src, num}, in place
    }
}

// ---------------- denom + hh: wave per node ----------------
__global__ __launch_bounds__(256) void denom_hh_kernel(
    const int* __restrict__ offsets, const int2* __restrict__ sortedPair,
    float* __restrict__ h, int N)
{
    int gw = (blockIdx.x * blockDim.x + threadIdx.x) >> 6;
    int lane = threadIdx.x & 63;
    if (gw >= N) return;
    int beg = offsets[gw], end = offsets[gw + 1];
    float s = 0.f;
    for (int e = beg + lane; e < end; e += 64) s += __int_as_float(sortedPair[e].y);
    #pragma unroll
    for (int off = 32; off; off >>= 1) s += __shfl_down(s, off);
    s = __shfl(s, 0);
    float inv = 1.f / (s + 1e-16f);
    float hv = h[(size_t)gw * 64 + lane];
    asm volatile("" ::: "memory");   // order read-before-aliased-write
    unsigned short* row = reinterpret_cast<unsigned short*>(h) + (size_t)gw * 128;
    row[lane] = f2bf(hv * inv);
}

// ---------------- aggregate: wave per dst node, 2 edges per gather ----------
// hh row = 64 bf16 in the first 32 dwords of a 64-dword fp32 row (base s*64).
__global__ __launch_bounds__(256) void aggregate_kernel(
    const int* __restrict__ offsets, const int2* __restrict__ sortedPair,
    const unsigned* __restrict__ hhW, const float* __restrict__ bias,
    float* __restrict__ out, int N)
{
    int gw = (blockIdx.x * blockDim.x + threadIdx.x) >> 6;
    int lane = threadIdx.x & 63;
    if (gw >= N) return;
    int beg = offsets[gw], end = offsets[gw + 1];
    const int half = lane >> 5;
    const int cp = lane & 31;
    float accx = 0.f, accy = 0.f;
    for (int e0 = beg; e0 < end; e0 += 64) {
        int idx = e0 + lane;
        int2 p = (idx < end) ? sortedPair[idx] : make_int2(0, 0);
        int cnt = min(64, end - e0);
        int j = 0;
        for (; j + 8 <= cnt; j += 8) {
            #pragma unroll
            for (int u = 0; u < 4; ++u) {
                int jj = j + 2 * u + half;
                int s = __shfl(p.x, jj);
                float wv = __shfl(__int_as_float(p.y), jj);
                unsigned g = hhW[(size_t)s * 64 + cp];
                accx = fmaf(bf2f((unsigned short)(g & 0xFFFFu)), wv, accx);
                accy = fmaf(bf2f((unsigned short)(g >> 16)), wv, accy);
            }
        }
        for (; j < cnt; j += 2) {
            int jj = j + half;
            bool v = jj < cnt;
            int s = __shfl(p.x, v ? jj : j);
            float wv = v ? __shfl(__int_as_float(p.y), jj) : 0.f;
            unsigned g = hhW[(size_t)s * 64 + cp];
            accx = fmaf(bf2f((unsigned short)(g & 0xFFFFu)), wv, accx);
            accy = fmaf(bf2f((unsigned short)(g >> 16)), wv, accy);
        }
    }
    accx += __shfl_xor(accx, 32);
    accy += __shfl_xor(accy, 32);
    if (lane < 32) {
        float2 b = reinterpret_cast<const float2*>(bias)[cp];
        float2 o; o.x = accx + b.x; o.y = accy + b.y;
        reinterpret_cast<float2*>(out)[(size_t)gw * 32 + cp] = o;
    }
}

extern "C" void kernel_launch(void* const* d_in, const int* in_sizes, int n_in,
                              void* d_out, int out_size, void* d_ws, size_t ws_size,
                              hipStream_t stream) {
    const float* x    = (const float*)d_in[0];
    const int*   ei   = (const int*)d_in[1];
    // d_in[2] = rank_mapping (unused)
    const float* W1   = (const float*)d_in[3];
    const float* Wp   = (const float*)d_in[4];
    const float* bp   = (const float*)d_in[5];
    const float* bias = (const float*)d_in[6];
    float* out = (float*)d_out;

    const int N = in_sizes[0] / 128;
    const int E = in_sizes[1] / 2;
    const int K = (N + 255) / 256;     // dst bins (391)
    const int M = K * 8;               // sub-bins (3128)

    // workspace (4B units):
    // h[N*64] | a[N] | b[N] | offsets[N+1] | cnt2[M] | subOffsets[M+1] |
    // subCursor[M] | staging[E] (int2, 8B-aligned)
    float* h          = (float*)d_ws;
    float* aArr       = h + (size_t)N * 64;
    float* bArr       = aArr + N;
    int*   offsets    = (int*)(bArr + N);
    int*   cnt2       = offsets + (N + 1);
    int*   subOffsets = cnt2 + M;
    int*   subCursor  = subOffsets + (M + 1);
    int*   stagingRaw = subCursor + M;
    // align to 8B
    stagingRaw = (int*)(((uintptr_t)stagingRaw + 7) & ~(uintptr_t)7);
    int2*  staging    = (int2*)stagingRaw;

    hipMemsetAsync(cnt2, 0, (size_t)M * sizeof(int), stream);

    node_transform_kernel<<<(N + 15) / 16, 256, 0, stream>>>(x, W1, Wp, h, aArr, bArr, N);

    subhist_kernel<<<(E + 255) / 256, 256, 0, stream>>>(ei, cnt2, E);

    subscan_kernel<<<1, 256, 0, stream>>>(cnt2, subOffsets, subCursor, offsets, M, N, E);

    binscatter_kernel<<<(E + 255) / 256, 256, 0, stream>>>(ei, aArr, bArr, bp,
                                                           subCursor, staging, E);

    localsort_kernel<<<K, 256, 0, stream>>>(subOffsets, staging, offsets, N);

    denom_hh_kernel<<<(N * 64 + 255) / 256, 256, 0, stream>>>(offsets, staging, h, N);

    aggregate_kernel<<<(N * 64 + 255) / 256, 256, 0, stream>>>(
        offsets, staging, reinterpret_cast<const unsigned*>(h), bias, out, N);
}